// Round 2
// baseline (205.943 us; speedup 1.0000x reference)
//
#include <hip/hip_runtime.h>
#include <hip/hip_bf16.h>

#define NN 50000
#define FIN 128
#define NT (NN / 16)   // 3125 row-tiles of 16
#define NREG 196       // ceil(NN/256) 256-node regions
#define SLAB 8960      // fixed per-region CSR slab (max padded region ~6500)
#define NSLH 512       // degree-histogram slices
#define NSLS 512       // scatter slices
#define NGEMB ((NT + 3) / 4)  // 782 GEMM blocks

typedef unsigned short u16;
typedef unsigned int u32;
typedef __attribute__((ext_vector_type(8))) short short8;
typedef __attribute__((ext_vector_type(4))) float floatx4;

__device__ __forceinline__ float b2f(u16 v) {
  union { u32 u; float f; } x; x.u = ((u32)v) << 16; return x.f;
}
__device__ __forceinline__ u16 f2b(float f) {
  union { u32 u; float f; } x; x.f = f;
  u32 r = x.u + 0x7FFFu + ((x.u >> 16) & 1u);  // round-nearest-even
  return (u16)(r >> 16);
}

// K0: fused prep + degree histogram.
// Blocks 0..31: W1 frag hi/lo tables (block 0 detects x/W1, publishes flags).
// Block 32: w2f = W2@Wfc, cbias, zero g sentinel row + tvec sentinel.
// Blocks 33..: cnt[dst]++ fire-and-forget histogram (no bucket, no gtail).
__global__ __launch_bounds__(256) void k_prep_hist(
    const u32* __restrict__ xw, int nxw, const void* __restrict__ w1, int n1w,
    const void* __restrict__ w2, int n2w, const void* __restrict__ wf, int nfw,
    const u16* __restrict__ b2, const u16* __restrict__ bfc,
    u16* __restrict__ W1h, u16* __restrict__ W1l, float* __restrict__ w2f,
    float* __restrict__ cbias, int* __restrict__ flags,
    const int* __restrict__ dst, int E, int* __restrict__ cnt,
    u16* __restrict__ g, float* __restrict__ tvec) {
  int t = threadIdx.x;
  int blk = blockIdx.x;
  if (blk >= 33) {  // ---- degree histogram ----
    int sl = blk - 33;
    int lo = (int)((long long)sl * E / NSLH);
    int hi = (int)((long long)(sl + 1) * E / NSLH);
    for (int e = lo + t; e < hi; e += 256) atomicAdd(&cnt[dst[e]], 1);
    return;
  }
  __shared__ int sc[2];
  if (t < 2) sc[t] = 0;
  __syncthreads();
  if (blk < 32) {  // ---- W1 frag tables ----
    const u32* p = (const u32*)w1;
    int samples = n1w < 1024 ? n1w : 1024;
    int score = 0;
    for (int i = t; i < samples; i += 256) {
      u32 w = p[i];
      u32 e = (w >> 7) & 0xFFu;
      score += (e >= 100u && e <= 132u) ? 1 : -1;
    }
    if (score) atomicAdd(&sc[0], score);
    if (blk == 0) {
      int sn = nxw < 1024 ? nxw : 1024;
      int sx = 0;
      for (int i = t; i < sn; i += 256) {
        u32 w = xw[i];
        u32 e = (w >> 7) & 0xFFu;
        sx += (e >= 100u && e <= 132u) ? 1 : -1;
      }
      if (sx) atomicAdd(&sc[1], sx);
    }
    __syncthreads();
    int f1 = sc[0] > 0;
    if (blk == 0 && t == 0) {
      flags[0] = sc[1] > 0;
      flags[1] = f1;
    }
    int i = blk * 256 + t;
    int j = i & 7, L = (i >> 3) & 63, f = i >> 9;
    int k = (f >> 2) * 32 + (L >> 4) * 8 + j;
    int n = (f & 3) * 16 + (L & 15);
    int idx = k * 64 + n;
    float v = f1 ? b2f(((const u16*)w1)[idx]) : ((const float*)w1)[idx];
    u16 hb = f2b(v);
    W1h[i] = hb;
    W1l[i] = f2b(v - b2f(hb));
  } else {  // ---- blk == 32: w2f, cbias, sentinels ----
    const u32* p2 = (const u32*)w2;
    const u32* pf = (const u32*)wf;
    int n2s = n2w < 1024 ? n2w : 1024;
    int nfs = nfw < 1024 ? nfw : 1024;
    int s2 = 0, sf = 0;
    for (int i = t; i < n2s; i += 256) {
      u32 w = p2[i];
      u32 e = (w >> 7) & 0xFFu;
      s2 += (e >= 100u && e <= 132u) ? 1 : -1;
    }
    for (int i = t; i < nfs; i += 256) {
      u32 w = pf[i];
      u32 e = (w >> 7) & 0xFFu;
      sf += (e >= 100u && e <= 132u) ? 1 : -1;
    }
    if (s2) atomicAdd(&sc[0], s2);
    if (sf) atomicAdd(&sc[1], sf);
    __syncthreads();
    int f2 = sc[0] > 0, f3 = sc[1] > 0;
    if (t == 0) { flags[2] = f2; flags[3] = f3; }
    if (t < 64) {
      float acc = 0.f;
      for (int j = 0; j < 64; ++j) {
        float w2v = f2 ? b2f(((const u16*)w2)[t * 64 + j])
                       : ((const float*)w2)[t * 64 + j];
        float wfv = f3 ? b2f(((const u16*)wf)[j]) : ((const float*)wf)[j];
        acc += w2v * wfv;
      }
      w2f[t] = acc;
    } else if (t == 64) {
      float acc = b2f(bfc[0]);
      for (int j = 0; j < 64; ++j) {
        float wfv = f3 ? b2f(((const u16*)wf)[j]) : ((const float*)wf)[j];
        acc += b2f(b2[j]) * wfv;
      }
      cbias[0] = acc;
    } else if (t >= 128 && t < 192) {
      g[(size_t)NN * 64 + (t - 128)] = 0;  // sentinel row g[NN] = 0
    } else if (t == 192) {
      tvec[NN] = 0.f;  // sentinel tscaled[NN] = 0
    }
  }
}

// K1: region-local padded scan -> rowstart + write-offset init + sentinel pad.
// Slab layout (region r at r*SLAB) -> no global scan needed. Sentinels occupy
// [rowstart+cnt, rowstart+pad16), disjoint from real entries written later.
__global__ __launch_bounds__(256) void k_scan(const int* __restrict__ cnt,
                                              int* __restrict__ rowstart,
                                              int* __restrict__ wo,
                                              u16* __restrict__ csr) {
  __shared__ int sm4[4];
  int r = blockIdx.x, t = threadIdx.x;
  int v = r * 256 + t;
  int c = (v < NN) ? cnt[v] : 0;
  int p = (c + 15) & ~15;
  int lane = t & 63, w = t >> 6;
  int xv = p;
  for (int d = 1; d < 64; d <<= 1) {
    int y = __shfl_up(xv, d);
    if (lane >= d) xv += y;
  }
  if (lane == 63) sm4[w] = xv;
  __syncthreads();
  int add = 0;
  for (int j = 0; j < w; ++j) add += sm4[j];
  xv += add;
  int grs = r * SLAB + xv - p;  // exclusive padded scan within slab
  if (v < NN) {
    rowstart[v] = grs;
    wo[v] = grs;
    for (int pos = grs + c; pos < grs + p; ++pos) csr[pos] = (u16)NN;
  }
}

// K2: blocks 0..NGEMB-1 = dinv-scaled split-bf16 MFMA GEMM g = bf16(dinv*x@W1)
// (cnt is complete, so scaling happens in the epilogue);
// blocks NGEMB.. = direct CSR scatter: csr[atomicAdd(&wo[dst],1)] = src.
// The two halves are independent and overlap (GEMM = MFMA-bound long pole,
// scatter = atomic-latency-bound with idle VALU).
__global__ __launch_bounds__(256) void k_gemm_scatter(
    const int* __restrict__ src, const int* __restrict__ dst, int E,
    int* __restrict__ wo, u16* __restrict__ csr,
    const void* __restrict__ X, const u16* __restrict__ Wh,
    const u16* __restrict__ Wl, const int* __restrict__ cnt,
    u16* __restrict__ g, const int* __restrict__ flags) {
  int t = threadIdx.x;
  if (blockIdx.x >= NGEMB) {  // ---- direct scatter ----
    int sl = blockIdx.x - NGEMB;
    int lo = (int)((long long)sl * E / NSLS);
    int hi = (int)((long long)(sl + 1) * E / NSLS);
    for (int e = lo + t; e < hi; e += 256) {
      int d = dst[e];
      int s = src[e];
      int pos = atomicAdd(&wo[d], 1);
      csr[pos] = (u16)s;
    }
    return;
  }
  // ---- GEMM: g = bf16(dinv[row] * (x @ W1)) ----
  constexpr int KC = FIN / 32;
  int wave = t >> 6, lane = t & 63;
  int rt = blockIdx.x * 4 + wave;
  if (rt >= NT) return;
  int m = rt * 16 + (lane & 15);
  int q = (lane >> 4) * 8;
  bool xb = flags[0] != 0;

  short8 ah[KC], al[KC];
  if (xb) {
    const u16* xr = (const u16*)X + (size_t)m * FIN + q;
#pragma unroll
    for (int kc = 0; kc < KC; ++kc) ah[kc] = *(const short8*)(xr + kc * 32);
  } else {
    const float* xr = (const float*)X + (size_t)m * FIN + q;
#pragma unroll
    for (int kc = 0; kc < KC; ++kc) {
      float4 v0 = *(const float4*)(xr + kc * 32);
      float4 v1 = *(const float4*)(xr + kc * 32 + 4);
      float v[8] = {v0.x, v0.y, v0.z, v0.w, v1.x, v1.y, v1.z, v1.w};
      short8 h8, l8;
#pragma unroll
      for (int j = 0; j < 8; ++j) {
        u16 hb = f2b(v[j]);
        h8[j] = (short)hb;
        l8[j] = (short)f2b(v[j] - b2f(hb));
      }
      ah[kc] = h8;
      al[kc] = l8;
    }
  }

  int row0 = rt * 16 + (lane >> 4) * 4;
  int c0 = lane & 15;
  float dvr[4];
#pragma unroll
  for (int r = 0; r < 4; ++r)
    dvr[r] = rsqrtf((float)(cnt[row0 + r] + 1));
#pragma unroll
  for (int ct = 0; ct < 4; ++ct) {
    short8 bh[KC], bl[KC];
#pragma unroll
    for (int kc = 0; kc < KC; ++kc) {
      size_t fo = ((size_t)((kc * 4 + ct) * 64 + lane)) * 8;
      bh[kc] = *(const short8*)(Wh + fo);
      bl[kc] = *(const short8*)(Wl + fo);
    }
    floatx4 acc = (floatx4)(0.f);
#pragma unroll
    for (int kc = 0; kc < KC; ++kc) {
      if (!xb)
        acc = __builtin_amdgcn_mfma_f32_16x16x32_bf16(al[kc], bh[kc], acc, 0, 0, 0);
      acc = __builtin_amdgcn_mfma_f32_16x16x32_bf16(ah[kc], bl[kc], acc, 0, 0, 0);
      acc = __builtin_amdgcn_mfma_f32_16x16x32_bf16(ah[kc], bh[kc], acc, 0, 0, 0);
    }
    size_t o = (size_t)row0 * 64 + ct * 16 + c0;
#pragma unroll
    for (int r = 0; r < 4; ++r) g[o + (size_t)r * 64] = f2b(acc[r] * dvr[r]);
  }
}

// K3: layer-1 agg + relu + head projection, FOUR nodes/wave (64 gathers in
// flight), add-only inner loop (weights folded into g):
//   tvec[v] = dinv[v] * ( relu( dv*(sum g[s] + g[v]) + b1 ) . w2f )
__global__ __launch_bounds__(256) void k_agg1t(const u16* __restrict__ g,
                                               const int* __restrict__ cnt,
                                               const int* __restrict__ rowstart,
                                               const u16* __restrict__ csr,
                                               const u16* __restrict__ bias,
                                               const float* __restrict__ w2f,
                                               float* __restrict__ tvec) {
  int tid = threadIdx.x;
  int wave = tid >> 6, lane = tid & 63;
  int v = (blockIdx.x * 4 + wave) * 4;  // NN%16==0 -> v+3 < NN
  int rs[4], pd[4];
  float dvl[4], acc[4];
  int pm = 0;
#pragma unroll
  for (int n = 0; n < 4; ++n) {
    rs[n] = rowstart[v + n];
    int c = cnt[v + n];
    pd[n] = (c + 15) & ~15;
    dvl[n] = rsqrtf((float)(c + 1));
    acc[n] = b2f(g[(size_t)(v + n) * 64 + lane]);  // self term
    pm = pd[n] > pm ? pd[n] : pm;
  }
  for (int j = 0; j < pm; j += 16) {
    u32 cw[4][8];
    bool act[4];
#pragma unroll
    for (int n = 0; n < 4; ++n) {
      act[n] = j < pd[n];
      if (act[n]) {
        int b = rs[n] + j;
        uint4 c0 = *(const uint4*)(csr + b);
        uint4 c1 = *(const uint4*)(csr + b + 8);
        cw[n][0] = c0.x; cw[n][1] = c0.y; cw[n][2] = c0.z; cw[n][3] = c0.w;
        cw[n][4] = c1.x; cw[n][5] = c1.y; cw[n][6] = c1.z; cw[n][7] = c1.w;
      }
    }
    float hh[4][16];
#pragma unroll
    for (int n = 0; n < 4; ++n) {
      if (act[n]) {
#pragma unroll
        for (int i = 0; i < 8; ++i) {
          hh[n][2 * i] = b2f(g[(size_t)(cw[n][i] & 0xFFFFu) * 64 + lane]);
          hh[n][2 * i + 1] = b2f(g[(size_t)(cw[n][i] >> 16) * 64 + lane]);
        }
      }
    }
#pragma unroll
    for (int n = 0; n < 4; ++n) {
      if (act[n]) {
        float s0 = (hh[n][0] + hh[n][1]) + (hh[n][2] + hh[n][3]);
        float s1 = (hh[n][4] + hh[n][5]) + (hh[n][6] + hh[n][7]);
        float s2 = (hh[n][8] + hh[n][9]) + (hh[n][10] + hh[n][11]);
        float s3 = (hh[n][12] + hh[n][13]) + (hh[n][14] + hh[n][15]);
        acc[n] += (s0 + s1) + (s2 + s3);
      }
    }
  }
  float bv = b2f(bias[lane]);
  float wfv = w2f[lane];
  float val[4];
#pragma unroll
  for (int n = 0; n < 4; ++n) {
    val[n] = fmaxf(dvl[n] * acc[n] + bv, 0.0f) * wfv;
    for (int o = 32; o > 0; o >>= 1) val[n] += __shfl_xor(val[n], o);
  }
#pragma unroll
  for (int n = 0; n < 4; ++n)
    if (lane == n) tvec[v + n] = dvl[n] * val[n];
}

// K4: scalar agg + sigmoid: four nodes/wave, 16 lanes each.
// z[v] = dv*(sum tscaled[s] + tscaled[v]) + cbias; sentinel pads add 0.
__global__ __launch_bounds__(256) void k_aggz(const float* __restrict__ tvec,
                                              const int* __restrict__ rowstart,
                                              const int* __restrict__ cnt,
                                              const u16* __restrict__ csr,
                                              const float* __restrict__ cbias,
                                              void* __restrict__ out,
                                              const int* __restrict__ flags) {
  int tid = threadIdx.x;
  int wave = tid >> 6, lane = tid & 63;
  int sub = lane >> 4, slot = lane & 15;
  int v = blockIdx.x * 16 + wave * 4 + sub;  // NN%16==0 -> v < NN
  int rs = rowstart[v];
  int cv = cnt[v];
  int pdeg = (cv + 15) & ~15;
  float acc = 0.f;
  for (int j = slot; j < pdeg; j += 16) acc += tvec[csr[rs + j]];
  for (int o = 8; o > 0; o >>= 1) acc += __shfl_xor(acc, o);
  if (slot == 0) {
    float dv = rsqrtf((float)(cv + 1));
    float z = dv * (acc + tvec[v]) + cbias[0];
    float sg = 1.0f / (1.0f + __expf(-z));
    if (flags[0]) ((u16*)out)[v] = f2b(sg);
    else ((float*)out)[v] = sg;
  }
}

extern "C" void kernel_launch(void* const* d_in, const int* in_sizes, int n_in,
                              void* d_out, int out_size, void* d_ws, size_t ws_size,
                              hipStream_t stream) {
  const void* x = d_in[0];
  const int* ei = (const int*)d_in[1];
  const void* W1 = d_in[2];
  const u16* b1 = (const u16*)d_in[3];
  const void* W2 = d_in[4];
  const u16* b2 = (const u16*)d_in[5];
  const void* Wfc = d_in[6];
  const u16* bfc = (const u16*)d_in[7];

  int E = in_sizes[1] / 2;
  const int* src = ei;
  const int* dst = ei + E;

  char* base = (char*)d_ws;
  size_t off = 0;
  auto alloc = [&](size_t bytes) {
    void* p = base + off;
    off = (off + bytes + 255) & ~(size_t)255;
    return p;
  };
  int* flags = (int*)alloc(8 * 4);
  u16* W1h = (u16*)alloc((size_t)FIN * 64 * 2);
  u16* W1l = (u16*)alloc((size_t)FIN * 64 * 2);
  float* w2f = (float*)alloc(64 * 4);
  float* cbias = (float*)alloc(4);
  int* cnt = (int*)alloc((size_t)NN * 4);
  int* rowstart = (int*)alloc((size_t)NN * 4);
  int* wo = (int*)alloc((size_t)NN * 4);
  u16* csr = (u16*)alloc((size_t)NREG * SLAB * 2);
  u16* g = (u16*)alloc((size_t)(NN + 1) * 64 * 2);  // dinv-scaled h1 + 0 row
  float* tvec = (float*)alloc((size_t)(NN + 1) * 4);  // tscaled + 0 sentinel

  hipMemsetAsync(cnt, 0, (size_t)NN * 4, stream);
  // K0) prep (frag tables, w2f, cbias, flags, sentinels) + degree histogram
  k_prep_hist<<<33 + NSLH, 256, 0, stream>>>(
      (const u32*)x, in_sizes[0] / 2, W1, in_sizes[2] / 2, W2, in_sizes[4] / 2,
      Wfc, in_sizes[6] / 2, b2, bfc, W1h, W1l, w2f, cbias, flags, dst, E, cnt,
      g, tvec);
  // K1) region-local padded scan -> rowstart/wo + sentinel pads
  k_scan<<<NREG, 256, 0, stream>>>(cnt, rowstart, wo, csr);
  // K2) dinv-scaled x@W1 MFMA GEMM (782 blocks) || direct CSR scatter (512)
  k_gemm_scatter<<<NGEMB + NSLS, 256, 0, stream>>>(src, dst, E, wo, csr, x,
                                                   W1h, W1l, cnt, g, flags);
  // K3) layer-1 agg + relu + head projection -> tscaled
  k_agg1t<<<NN / 16, 256, 0, stream>>>(g, cnt, rowstart, csr, b1, w2f, tvec);
  // K4) scalar agg + sigmoid -> out
  k_aggz<<<NN / 16, 256, 0, stream>>>(tvec, rowstart, cnt, csr, cbias, d_out,
                                      flags);
}

// Round 3
// 178.073 us; speedup vs baseline: 1.1565x; 1.1565x over previous
//
#include <hip/hip_runtime.h>
#include <hip/hip_bf16.h>

#define NN 50000
#define FIN 128
#define NT (NN / 16)   // 3125 row-tiles of 16
#define NREG 196       // ceil(NN/256) 256-node regions
#define SLAB 8960      // fixed per-region CSR slab (max padded region ~8150)
#define NBINA 512      // binA edge slices (2 blocks/CU -> TLP)
#define NGRP 8         // gtail shards (blockIdx&7 ~ XCD round-robin)
#define SUBCAP 768     // per-(group,region) bucket capacity (mean 512, +11simga)
#define NGEMB ((NT + 3) / 4)  // 782 GEMM blocks

typedef unsigned short u16;
typedef unsigned int u32;
typedef __attribute__((ext_vector_type(8))) short short8;
typedef __attribute__((ext_vector_type(4))) float floatx4;

__device__ __forceinline__ float b2f(u16 v) {
  union { u32 u; float f; } x; x.u = ((u32)v) << 16; return x.f;
}
__device__ __forceinline__ u16 f2b(float f) {
  union { u32 u; float f; } x; x.f = f;
  u32 r = x.u + 0x7FFFu + ((x.u >> 16) & 1u);  // round-nearest-even
  return (u16)(r >> 16);
}

// K0: fused prep + bucket binning.
// Blocks 0..31: W1 frag hi/lo tables (block 0 detects x/W1, publishes flags).
// Block 32: w2f = W2@Wfc, cbias, zero g sentinel row + tvec sentinel.
// Blocks 33..: binA. Reservation counter gtail8 is sharded 8 ways by
// blockIdx&7 so each shard's line stays in one XCD's L2 (kills the 256-deep
// cross-XCD RMW convoy that made the unsharded version 44+ us). Each shard
// owns its own bucket sub-slab. cnt[dst]++ rides along (fire-and-forget).
__global__ __launch_bounds__(256) void k_prep_binA(
    const u32* __restrict__ xw, int nxw, const void* __restrict__ w1, int n1w,
    const void* __restrict__ w2, int n2w, const void* __restrict__ wf, int nfw,
    const u16* __restrict__ b2, const u16* __restrict__ bfc,
    u16* __restrict__ W1h, u16* __restrict__ W1l, float* __restrict__ w2f,
    float* __restrict__ cbias, int* __restrict__ flags,
    const int* __restrict__ src, const int* __restrict__ dst, int E,
    u32* __restrict__ bucket, int* __restrict__ gtail8, int* __restrict__ cnt,
    u16* __restrict__ g, float* __restrict__ tvec) {
  int t = threadIdx.x;
  int blk = blockIdx.x;
  if (blk >= 33) {  // ---- binA ----
    __shared__ int hist[NREG];
    __shared__ int base[NREG];
    __shared__ int hist2[NREG];
    for (int i = t; i < NREG; i += 256) { hist[i] = 0; hist2[i] = 0; }
    __syncthreads();
    int sl = blk - 33;
    int lo = (int)((long long)sl * E / NBINA);
    int hi = (int)((long long)(sl + 1) * E / NBINA);
    for (int e = lo + t; e < hi; e += 256) {
      int d = dst[e];
      atomicAdd(&hist[d >> 8], 1);
      atomicAdd(&cnt[d], 1);  // fire-and-forget degree count (16/addr, no convoy)
    }
    __syncthreads();
    int grp = blk & (NGRP - 1);
    for (int i = t; i < NREG; i += 256) {
      int c = hist[i];
      base[i] = (c > 0) ? atomicAdd(&gtail8[grp * NREG + i], c) : 0;
    }
    __syncthreads();
    for (int e = lo + t; e < hi; e += 256) {
      int d = dst[e];
      int r = d >> 8;
      int ofs = base[r] + atomicAdd(&hist2[r], 1);
      if (ofs < SUBCAP)
        bucket[(size_t)(grp * NREG + r) * SUBCAP + ofs] =
            ((u32)(d & 255) << 16) | (u32)src[e];
    }
    return;
  }
  __shared__ int sc[2];
  if (t < 2) sc[t] = 0;
  __syncthreads();
  if (blk < 32) {  // ---- W1 frag tables ----
    const u32* p = (const u32*)w1;
    int samples = n1w < 1024 ? n1w : 1024;
    int score = 0;
    for (int i = t; i < samples; i += 256) {
      u32 w = p[i];
      u32 e = (w >> 7) & 0xFFu;
      score += (e >= 100u && e <= 132u) ? 1 : -1;
    }
    if (score) atomicAdd(&sc[0], score);
    if (blk == 0) {
      int sn = nxw < 1024 ? nxw : 1024;
      int sx = 0;
      for (int i = t; i < sn; i += 256) {
        u32 w = xw[i];
        u32 e = (w >> 7) & 0xFFu;
        sx += (e >= 100u && e <= 132u) ? 1 : -1;
      }
      if (sx) atomicAdd(&sc[1], sx);
    }
    __syncthreads();
    int f1 = sc[0] > 0;
    if (blk == 0 && t == 0) {
      flags[0] = sc[1] > 0;
      flags[1] = f1;
    }
    int i = blk * 256 + t;
    int j = i & 7, L = (i >> 3) & 63, f = i >> 9;
    int k = (f >> 2) * 32 + (L >> 4) * 8 + j;
    int n = (f & 3) * 16 + (L & 15);
    int idx = k * 64 + n;
    float v = f1 ? b2f(((const u16*)w1)[idx]) : ((const float*)w1)[idx];
    u16 hb = f2b(v);
    W1h[i] = hb;
    W1l[i] = f2b(v - b2f(hb));
  } else {  // ---- blk == 32: w2f, cbias, sentinels ----
    const u32* p2 = (const u32*)w2;
    const u32* pf = (const u32*)wf;
    int n2s = n2w < 1024 ? n2w : 1024;
    int nfs = nfw < 1024 ? nfw : 1024;
    int s2 = 0, sf = 0;
    for (int i = t; i < n2s; i += 256) {
      u32 w = p2[i];
      u32 e = (w >> 7) & 0xFFu;
      s2 += (e >= 100u && e <= 132u) ? 1 : -1;
    }
    for (int i = t; i < nfs; i += 256) {
      u32 w = pf[i];
      u32 e = (w >> 7) & 0xFFu;
      sf += (e >= 100u && e <= 132u) ? 1 : -1;
    }
    if (s2) atomicAdd(&sc[0], s2);
    if (sf) atomicAdd(&sc[1], sf);
    __syncthreads();
    int f2 = sc[0] > 0, f3 = sc[1] > 0;
    if (t == 0) { flags[2] = f2; flags[3] = f3; }
    if (t < 64) {
      float acc = 0.f;
      for (int j = 0; j < 64; ++j) {
        float w2v = f2 ? b2f(((const u16*)w2)[t * 64 + j])
                       : ((const float*)w2)[t * 64 + j];
        float wfv = f3 ? b2f(((const u16*)wf)[j]) : ((const float*)wf)[j];
        acc += w2v * wfv;
      }
      w2f[t] = acc;
    } else if (t == 64) {
      float acc = b2f(bfc[0]);
      for (int j = 0; j < 64; ++j) {
        float wfv = f3 ? b2f(((const u16*)wf)[j]) : ((const float*)wf)[j];
        acc += b2f(b2[j]) * wfv;
      }
      cbias[0] = acc;
    } else if (t >= 128 && t < 192) {
      g[(size_t)NN * 64 + (t - 128)] = 0;  // sentinel row g[NN] = 0
    } else if (t == 192) {
      tvec[NN] = 0.f;  // sentinel tscaled[NN] = 0
    }
  }
}

// K1: blocks 0..195 = region scan (cnt -> rowstart) + CSR scatter from the 8
// bucket sub-slabs + sentinel pad; blocks 196.. = dinv-scaled split-bf16 MFMA
// GEMM g = bf16(dinv * x@W1). Independent halves overlap.
__global__ __launch_bounds__(256) void k_gemm_scatter(
    const u32* __restrict__ bucket, const int* __restrict__ gtail8,
    int* __restrict__ rowstart, const int* __restrict__ cnt,
    u16* __restrict__ csr,
    const void* __restrict__ X, const u16* __restrict__ Wh,
    const u16* __restrict__ Wl, u16* __restrict__ g,
    const int* __restrict__ flags) {
  int t = threadIdx.x;
  if (blockIdx.x < NREG) {  // ---- scan + scatter + pad ----
    __shared__ int off[256];
    __shared__ int sm4[4];
    int r = blockIdx.x;
    int v = r * 256 + t;
    int c = (v < NN) ? cnt[v] : 0;
    int p = (c + 15) & ~15;
    int lane = t & 63, w = t >> 6;
    int xv = p;
    for (int d = 1; d < 64; d <<= 1) {
      int y = __shfl_up(xv, d);
      if (lane >= d) xv += y;
    }
    if (lane == 63) sm4[w] = xv;
    __syncthreads();
    int add = 0;
    for (int j2 = 0; j2 < w; ++j2) add += sm4[j2];
    xv += add;
    int grs = r * SLAB + xv - p;  // exclusive padded scan within slab
    if (v < NN) rowstart[v] = grs;
    off[t] = grs;
    __syncthreads();
    for (int grp = 0; grp < NGRP; ++grp) {
      int n = gtail8[grp * NREG + r];
      if (n > SUBCAP) n = SUBCAP;
      const u32* b = bucket + (size_t)(grp * NREG + r) * SUBCAP;
      for (int i = t; i < n; i += 256) {
        u32 pk = b[i];
        int pos = atomicAdd(&off[pk >> 16], 1);
        csr[pos] = (u16)(pk & 0xFFFFu);
      }
    }
    __syncthreads();
    if (v < NN) {
      int end = grs + p;
      for (int pos = off[t]; pos < end; ++pos) csr[pos] = (u16)NN;  // sentinel
    }
    return;
  }
  // ---- GEMM: g = bf16(dinv[row] * (x @ W1)) ----
  constexpr int KC = FIN / 32;
  int wave = t >> 6, lane = t & 63;
  int rt = (blockIdx.x - NREG) * 4 + wave;
  if (rt >= NT) return;
  int m = rt * 16 + (lane & 15);
  int q = (lane >> 4) * 8;
  bool xb = flags[0] != 0;

  short8 ah[KC], al[KC];
  if (xb) {
    const u16* xr = (const u16*)X + (size_t)m * FIN + q;
#pragma unroll
    for (int kc = 0; kc < KC; ++kc) ah[kc] = *(const short8*)(xr + kc * 32);
  } else {
    const float* xr = (const float*)X + (size_t)m * FIN + q;
#pragma unroll
    for (int kc = 0; kc < KC; ++kc) {
      float4 v0 = *(const float4*)(xr + kc * 32);
      float4 v1 = *(const float4*)(xr + kc * 32 + 4);
      float v[8] = {v0.x, v0.y, v0.z, v0.w, v1.x, v1.y, v1.z, v1.w};
      short8 h8, l8;
#pragma unroll
      for (int j = 0; j < 8; ++j) {
        u16 hb = f2b(v[j]);
        h8[j] = (short)hb;
        l8[j] = (short)f2b(v[j] - b2f(hb));
      }
      ah[kc] = h8;
      al[kc] = l8;
    }
  }

  int row0 = rt * 16 + (lane >> 4) * 4;
  int c0 = lane & 15;
  float dvr[4];
#pragma unroll
  for (int r = 0; r < 4; ++r)
    dvr[r] = rsqrtf((float)(cnt[row0 + r] + 1));
#pragma unroll
  for (int ct = 0; ct < 4; ++ct) {
    short8 bh[KC], bl[KC];
#pragma unroll
    for (int kc = 0; kc < KC; ++kc) {
      size_t fo = ((size_t)((kc * 4 + ct) * 64 + lane)) * 8;
      bh[kc] = *(const short8*)(Wh + fo);
      bl[kc] = *(const short8*)(Wl + fo);
    }
    floatx4 acc = (floatx4)(0.f);
#pragma unroll
    for (int kc = 0; kc < KC; ++kc) {
      if (!xb)
        acc = __builtin_amdgcn_mfma_f32_16x16x32_bf16(al[kc], bh[kc], acc, 0, 0, 0);
      acc = __builtin_amdgcn_mfma_f32_16x16x32_bf16(ah[kc], bl[kc], acc, 0, 0, 0);
      acc = __builtin_amdgcn_mfma_f32_16x16x32_bf16(ah[kc], bh[kc], acc, 0, 0, 0);
    }
    size_t o = (size_t)row0 * 64 + ct * 16 + c0;
#pragma unroll
    for (int r = 0; r < 4; ++r) g[o + (size_t)r * 64] = f2b(acc[r] * dvr[r]);
  }
}

// K2: layer-1 agg + relu + head projection, FOUR nodes/wave (64 gathers in
// flight), add-only inner loop (weights folded into g):
//   tvec[v] = dinv[v] * ( relu( dv*(sum g[s] + g[v]) + b1 ) . w2f )
__global__ __launch_bounds__(256) void k_agg1t(const u16* __restrict__ g,
                                               const int* __restrict__ cnt,
                                               const int* __restrict__ rowstart,
                                               const u16* __restrict__ csr,
                                               const u16* __restrict__ bias,
                                               const float* __restrict__ w2f,
                                               float* __restrict__ tvec) {
  int tid = threadIdx.x;
  int wave = tid >> 6, lane = tid & 63;
  int v = (blockIdx.x * 4 + wave) * 4;  // NN%16==0 -> v+3 < NN
  int rs[4], pd[4];
  float dvl[4], acc[4];
  int pm = 0;
#pragma unroll
  for (int n = 0; n < 4; ++n) {
    rs[n] = rowstart[v + n];
    int c = cnt[v + n];
    pd[n] = (c + 15) & ~15;
    dvl[n] = rsqrtf((float)(c + 1));
    acc[n] = b2f(g[(size_t)(v + n) * 64 + lane]);  // self term
    pm = pd[n] > pm ? pd[n] : pm;
  }
  for (int j = 0; j < pm; j += 16) {
    u32 cw[4][8];
    bool act[4];
#pragma unroll
    for (int n = 0; n < 4; ++n) {
      act[n] = j < pd[n];
      if (act[n]) {
        int b = rs[n] + j;
        uint4 c0 = *(const uint4*)(csr + b);
        uint4 c1 = *(const uint4*)(csr + b + 8);
        cw[n][0] = c0.x; cw[n][1] = c0.y; cw[n][2] = c0.z; cw[n][3] = c0.w;
        cw[n][4] = c1.x; cw[n][5] = c1.y; cw[n][6] = c1.z; cw[n][7] = c1.w;
      }
    }
    float hh[4][16];
#pragma unroll
    for (int n = 0; n < 4; ++n) {
      if (act[n]) {
#pragma unroll
        for (int i = 0; i < 8; ++i) {
          hh[n][2 * i] = b2f(g[(size_t)(cw[n][i] & 0xFFFFu) * 64 + lane]);
          hh[n][2 * i + 1] = b2f(g[(size_t)(cw[n][i] >> 16) * 64 + lane]);
        }
      }
    }
#pragma unroll
    for (int n = 0; n < 4; ++n) {
      if (act[n]) {
        float s0 = (hh[n][0] + hh[n][1]) + (hh[n][2] + hh[n][3]);
        float s1 = (hh[n][4] + hh[n][5]) + (hh[n][6] + hh[n][7]);
        float s2 = (hh[n][8] + hh[n][9]) + (hh[n][10] + hh[n][11]);
        float s3 = (hh[n][12] + hh[n][13]) + (hh[n][14] + hh[n][15]);
        acc[n] += (s0 + s1) + (s2 + s3);
      }
    }
  }
  float bv = b2f(bias[lane]);
  float wfv = w2f[lane];
  float val[4];
#pragma unroll
  for (int n = 0; n < 4; ++n) {
    val[n] = fmaxf(dvl[n] * acc[n] + bv, 0.0f) * wfv;
    for (int o = 32; o > 0; o >>= 1) val[n] += __shfl_xor(val[n], o);
  }
#pragma unroll
  for (int n = 0; n < 4; ++n)
    if (lane == n) tvec[v + n] = dvl[n] * val[n];
}

// K3: scalar agg + sigmoid: four nodes/wave, 16 lanes each.
// z[v] = dv*(sum tscaled[s] + tscaled[v]) + cbias; sentinel pads add 0.
__global__ __launch_bounds__(256) void k_aggz(const float* __restrict__ tvec,
                                              const int* __restrict__ rowstart,
                                              const int* __restrict__ cnt,
                                              const u16* __restrict__ csr,
                                              const float* __restrict__ cbias,
                                              void* __restrict__ out,
                                              const int* __restrict__ flags) {
  int tid = threadIdx.x;
  int wave = tid >> 6, lane = tid & 63;
  int sub = lane >> 4, slot = lane & 15;
  int v = blockIdx.x * 16 + wave * 4 + sub;  // NN%16==0 -> v < NN
  int rs = rowstart[v];
  int cv = cnt[v];
  int pdeg = (cv + 15) & ~15;
  float acc = 0.f;
  for (int j = slot; j < pdeg; j += 16) acc += tvec[csr[rs + j]];
  for (int o = 8; o > 0; o >>= 1) acc += __shfl_xor(acc, o);
  if (slot == 0) {
    float dv = rsqrtf((float)(cv + 1));
    float z = dv * (acc + tvec[v]) + cbias[0];
    float sg = 1.0f / (1.0f + __expf(-z));
    if (flags[0]) ((u16*)out)[v] = f2b(sg);
    else ((float*)out)[v] = sg;
  }
}

extern "C" void kernel_launch(void* const* d_in, const int* in_sizes, int n_in,
                              void* d_out, int out_size, void* d_ws, size_t ws_size,
                              hipStream_t stream) {
  const void* x = d_in[0];
  const int* ei = (const int*)d_in[1];
  const void* W1 = d_in[2];
  const u16* b1 = (const u16*)d_in[3];
  const void* W2 = d_in[4];
  const u16* b2 = (const u16*)d_in[5];
  const void* Wfc = d_in[6];
  const u16* bfc = (const u16*)d_in[7];

  int E = in_sizes[1] / 2;
  const int* src = ei;
  const int* dst = ei + E;

  char* base = (char*)d_ws;
  size_t off = 0;
  auto alloc = [&](size_t bytes) {
    void* p = base + off;
    off = (off + bytes + 255) & ~(size_t)255;
    return p;
  };
  int* flags = (int*)alloc(8 * 4);
  u16* W1h = (u16*)alloc((size_t)FIN * 64 * 2);
  u16* W1l = (u16*)alloc((size_t)FIN * 64 * 2);
  float* w2f = (float*)alloc(64 * 4);
  float* cbias = (float*)alloc(4);
  int* rowstart = (int*)alloc((size_t)NN * 4);
  int* gtail8 = (int*)alloc((size_t)NGRP * NREG * 4);  // gtail8+cnt contiguous
  int* cnt = (int*)alloc((size_t)NN * 4);              //   -> one memset
  u32* bucket = (u32*)alloc((size_t)NGRP * NREG * SUBCAP * 4);
  u16* csr = (u16*)alloc((size_t)NREG * SLAB * 2);
  u16* g = (u16*)alloc((size_t)(NN + 1) * 64 * 2);  // dinv-scaled h1 + 0 row
  float* tvec = (float*)alloc((size_t)(NN + 1) * 4);  // tscaled + 0 sentinel

  size_t zbytes = (size_t)((char*)(cnt + NN) - (char*)gtail8);
  hipMemsetAsync(gtail8, 0, zbytes, stream);  // zeroes gtail8 AND cnt
  // K0) prep (frag tables, w2f, cbias, flags, sentinels) + sharded binA
  k_prep_binA<<<33 + NBINA, 256, 0, stream>>>(
      (const u32*)x, in_sizes[0] / 2, W1, in_sizes[2] / 2, W2, in_sizes[4] / 2,
      Wfc, in_sizes[6] / 2, b2, bfc, W1h, W1l, w2f, cbias, flags, src, dst, E,
      bucket, gtail8, cnt, g, tvec);
  // K1) region scan->rowstart + CSR scatter+pad (196) || MFMA GEMM (782)
  k_gemm_scatter<<<NREG + NGEMB, 256, 0, stream>>>(
      bucket, gtail8, rowstart, cnt, csr, x, W1h, W1l, g, flags);
  // K2) layer-1 agg + relu + head projection -> tscaled
  k_agg1t<<<NN / 16, 256, 0, stream>>>(g, cnt, rowstart, csr, b1, w2f, tvec);
  // K3) scalar agg + sigmoid -> out
  k_aggz<<<NN / 16, 256, 0, stream>>>(tvec, rowstart, cnt, csr, cbias, d_out,
                                      flags);
}

// Round 4
// 162.342 us; speedup vs baseline: 1.2686x; 1.0969x over previous
//
#include <hip/hip_runtime.h>
#include <hip/hip_bf16.h>

#define NN 50000
#define FIN 128
#define NT (NN / 16)   // 3125 row-tiles of 16
#define NREG 196       // ceil(NN/256) 256-node regions
#define SLAB 8960      // fixed per-region CSR slab (max padded region ~8150)
#define NBINB 512      // binA chunks (1562 edges each)
#define CAP2 32        // per-(chunk,region) cell capacity = one 128B line
                       // (mean 7.97, P(>32) ~ 1e-11 per cell)
#define NGEMB ((NT + 3) / 4)  // 782 GEMM blocks
#define STCAP 5200     // LDS stage capacity (region mean 4082, +17 sigma)

typedef unsigned char u8;
typedef unsigned short u16;
typedef unsigned int u32;
typedef __attribute__((ext_vector_type(8))) short short8;
typedef __attribute__((ext_vector_type(4))) float floatx4;

__device__ __forceinline__ float b2f(u16 v) {
  union { u32 u; float f; } x; x.u = ((u32)v) << 16; return x.f;
}
__device__ __forceinline__ u16 f2b(float f) {
  union { u32 u; float f; } x; x.f = f;
  u32 r = x.u + 0x7FFFu + ((x.u >> 16) & 1u);  // round-nearest-even
  return (u16)(r >> 16);
}

// K0: three independent parts in one launch (no cross-block deps):
//  blk 0            : w2f = W2@Wfc, cbias, flags[0] (x fmt), sentinels.
//  blk 1..NBINB     : one-pass edge binning into fixed (chunk,region) cells.
//                     No global atomics, no reservation, single edge read.
//  blk NBINB+1..    : self-contained MFMA GEMM  gf = x @ W1  (f32, UNSCALED;
//                     degree scale is applied in K1). Each block detects the
//                     x/W1 formats and builds its own W1 frag tables in LDS.
__global__ __launch_bounds__(256) void k_prep_bin_gemm(
    const u32* __restrict__ xw, int nxw, const void* __restrict__ w1, int n1w,
    const void* __restrict__ w2, int n2w, const void* __restrict__ wf, int nfw,
    const u16* __restrict__ b2, const u16* __restrict__ bfc,
    float* __restrict__ w2f, float* __restrict__ cbias, int* __restrict__ flags,
    const int* __restrict__ src, const int* __restrict__ dst, int E,
    u32* __restrict__ bucket, u8* __restrict__ cntm,
    const void* __restrict__ X, float* __restrict__ gf,
    u16* __restrict__ g, float* __restrict__ tvec) {
  int t = threadIdx.x;
  int blk = blockIdx.x;
  if (blk >= 1 && blk <= NBINB) {  // ---- one-pass binning ----
    __shared__ int cnt2[NREG];
    for (int i = t; i < NREG; i += 256) cnt2[i] = 0;
    __syncthreads();
    int sl = blk - 1;
    int lo = (int)((long long)sl * E / NBINB);
    int hi = (int)((long long)(sl + 1) * E / NBINB);
    for (int e = lo + t; e < hi; e += 256) {
      int d = dst[e];
      int s = src[e];
      int r = d >> 8;
      int ofs = atomicAdd(&cnt2[r], 1);
      if (ofs < CAP2)
        bucket[((size_t)sl * NREG + r) * CAP2 + ofs] =
            ((u32)(d & 255) << 16) | (u32)s;
    }
    __syncthreads();
    for (int i = t; i < NREG; i += 256) {
      int c = cnt2[i];
      cntm[(size_t)sl * NREG + i] = (u8)(c > CAP2 ? CAP2 : c);
    }
    return;
  }
  if (blk == 0) {  // ---- misc: flags, w2f, cbias, sentinels ----
    __shared__ int sc[3];
    if (t < 3) sc[t] = 0;
    __syncthreads();
    const u32* p2 = (const u32*)w2;
    const u32* pf = (const u32*)wf;
    int n2s = n2w < 1024 ? n2w : 1024;
    int nfs = nfw < 1024 ? nfw : 1024;
    int sn = nxw < 1024 ? nxw : 1024;
    int s2 = 0, sf = 0, sx = 0;
    for (int i = t; i < n2s; i += 256) {
      u32 w = p2[i];
      u32 e = (w >> 7) & 0xFFu;
      s2 += (e >= 100u && e <= 132u) ? 1 : -1;
    }
    for (int i = t; i < nfs; i += 256) {
      u32 w = pf[i];
      u32 e = (w >> 7) & 0xFFu;
      sf += (e >= 100u && e <= 132u) ? 1 : -1;
    }
    for (int i = t; i < sn; i += 256) {
      u32 w = xw[i];
      u32 e = (w >> 7) & 0xFFu;
      sx += (e >= 100u && e <= 132u) ? 1 : -1;
    }
    if (s2) atomicAdd(&sc[0], s2);
    if (sf) atomicAdd(&sc[1], sf);
    if (sx) atomicAdd(&sc[2], sx);
    __syncthreads();
    int f2 = sc[0] > 0, f3 = sc[1] > 0;
    if (t == 0) { flags[0] = sc[2] > 0; flags[2] = f2; flags[3] = f3; }
    if (t < 64) {
      float acc = 0.f;
      for (int j = 0; j < 64; ++j) {
        float w2v = f2 ? b2f(((const u16*)w2)[t * 64 + j])
                       : ((const float*)w2)[t * 64 + j];
        float wfv = f3 ? b2f(((const u16*)wf)[j]) : ((const float*)wf)[j];
        acc += w2v * wfv;
      }
      w2f[t] = acc;
    } else if (t == 64) {
      float acc = b2f(bfc[0]);
      for (int j = 0; j < 64; ++j) {
        float wfv = f3 ? b2f(((const u16*)wf)[j]) : ((const float*)wf)[j];
        acc += b2f(b2[j]) * wfv;
      }
      cbias[0] = acc;
    } else if (t >= 128 && t < 192) {
      g[(size_t)NN * 64 + (t - 128)] = 0;  // sentinel row g[NN] = 0
    } else if (t == 192) {
      tvec[NN] = 0.f;  // sentinel tscaled[NN] = 0
    }
    return;
  }
  // ---- GEMM: gf = x @ W1 (f32, unscaled) ----
  __shared__ u16 lwh[FIN * 64];
  __shared__ u16 lwl[FIN * 64];
  __shared__ int scg[2];
  if (t < 2) scg[t] = 0;
  __syncthreads();
  {  // self-detect x / W1 formats (deterministic, same result in every block)
    int sn = nxw < 1024 ? nxw : 1024;
    int sx = 0;
    for (int i = t; i < sn; i += 256) {
      u32 w = xw[i];
      u32 e = (w >> 7) & 0xFFu;
      sx += (e >= 100u && e <= 132u) ? 1 : -1;
    }
    if (sx) atomicAdd(&scg[0], sx);
    int s1n = n1w < 1024 ? n1w : 1024;
    const u32* p1 = (const u32*)w1;
    int s1 = 0;
    for (int i = t; i < s1n; i += 256) {
      u32 w = p1[i];
      u32 e = (w >> 7) & 0xFFu;
      s1 += (e >= 100u && e <= 132u) ? 1 : -1;
    }
    if (s1) atomicAdd(&scg[1], s1);
  }
  __syncthreads();
  bool xb = scg[0] > 0;
  bool w1b = scg[1] > 0;
  // build split-bf16 W1 frag tables in LDS (same layout as the old global
  // tables: frag element j of short8 at offset i corresponds to
  // W1[kc*32 + (lane>>4)*8 + j][ct*16 + (lane&15)])
  for (int i = t; i < FIN * 64; i += 256) {
    int j = i & 7, L = (i >> 3) & 63, f = i >> 9;
    int k = (f >> 2) * 32 + (L >> 4) * 8 + j;
    int n = (f & 3) * 16 + (L & 15);
    int idx = k * 64 + n;
    float v = w1b ? b2f(((const u16*)w1)[idx]) : ((const float*)w1)[idx];
    u16 hb = f2b(v);
    lwh[i] = hb;
    lwl[i] = f2b(v - b2f(hb));
  }
  __syncthreads();
  constexpr int KC = FIN / 32;
  int wave = t >> 6, lane = t & 63;
  int rt = (blk - NBINB - 1) * 4 + wave;
  if (rt < NT) {
    int m = rt * 16 + (lane & 15);
    int q = (lane >> 4) * 8;
    short8 ah[KC], al[KC];
    if (xb) {
      const u16* xr = (const u16*)X + (size_t)m * FIN + q;
#pragma unroll
      for (int kc = 0; kc < KC; ++kc) ah[kc] = *(const short8*)(xr + kc * 32);
    } else {
      const float* xr = (const float*)X + (size_t)m * FIN + q;
#pragma unroll
      for (int kc = 0; kc < KC; ++kc) {
        float4 v0 = *(const float4*)(xr + kc * 32);
        float4 v1 = *(const float4*)(xr + kc * 32 + 4);
        float v[8] = {v0.x, v0.y, v0.z, v0.w, v1.x, v1.y, v1.z, v1.w};
        short8 h8, l8;
#pragma unroll
        for (int j = 0; j < 8; ++j) {
          u16 hb = f2b(v[j]);
          h8[j] = (short)hb;
          l8[j] = (short)f2b(v[j] - b2f(hb));
        }
        ah[kc] = h8;
        al[kc] = l8;
      }
    }
    int row0 = rt * 16 + (lane >> 4) * 4;
    int c0 = lane & 15;
#pragma unroll
    for (int ct = 0; ct < 4; ++ct) {
      short8 bh[KC], bl[KC];
#pragma unroll
      for (int kc = 0; kc < KC; ++kc) {
        int fo = ((kc * 4 + ct) * 64 + lane) * 8;
        bh[kc] = *(const short8*)(lwh + fo);
        bl[kc] = *(const short8*)(lwl + fo);
      }
      floatx4 acc = (floatx4)(0.f);
#pragma unroll
      for (int kc = 0; kc < KC; ++kc) {
        if (!xb)
          acc = __builtin_amdgcn_mfma_f32_16x16x32_bf16(al[kc], bh[kc], acc, 0, 0, 0);
        acc = __builtin_amdgcn_mfma_f32_16x16x32_bf16(ah[kc], bl[kc], acc, 0, 0, 0);
        acc = __builtin_amdgcn_mfma_f32_16x16x32_bf16(ah[kc], bh[kc], acc, 0, 0, 0);
      }
      size_t o = (size_t)row0 * 64 + ct * 16 + c0;
#pragma unroll
      for (int r = 0; r < 4; ++r) gf[o + (size_t)r * 64] = acc[r];
    }
  }
}

// K1: one block per region (512 thr). Scan 512 chunk counts -> gather cells
// into LDS stage -> node histogram -> rowstart/cnt -> csr scatter + sentinel
// pad -> dinv-scale gf (f32) into g (bf16) for this region's 256 rows.
__global__ __launch_bounds__(512) void k_assemble(
    const u32* __restrict__ bucket, const u8* __restrict__ cntm,
    int* __restrict__ rowstart, int* __restrict__ cnt, u16* __restrict__ csr,
    const float* __restrict__ gf, u16* __restrict__ g) {
  __shared__ u32 stage[STCAP];
  __shared__ int h[256];
  __shared__ int off[256];
  __shared__ int wsum[8];
  __shared__ int nws[4];
  __shared__ int tot_s;
  int r = blockIdx.x, t = threadIdx.x;
  int lane = t & 63, w = t >> 6;
  // chunk counts + 512-wide padless scan (8 waves)
  int c = (int)cntm[(size_t)t * NREG + r];
  int xv = c;
  for (int d = 1; d < 64; d <<= 1) {
    int y = __shfl_up(xv, d);
    if (lane >= d) xv += y;
  }
  if (lane == 63) wsum[w] = xv;
  if (t < 256) h[t] = 0;
  __syncthreads();
  int add = 0;
  for (int j = 0; j < w; ++j) add += wsum[j];
  int beg = xv + add - c;  // exclusive start of this chunk in stage
  if (t == 0) {
    int tt = 0;
    for (int j = 0; j < 8; ++j) tt += wsum[j];
    tot_s = tt > STCAP ? STCAP : tt;
  }
  // gather this chunk's cell (<= one 128B line) into stage
  const u32* b = bucket + ((size_t)t * NREG + r) * CAP2;
  for (int i = 0; i < c; ++i) {
    int p = beg + i;
    if (p < STCAP) stage[p] = b[i];
  }
  __syncthreads();
  int tot = tot_s;
  // node-level histogram
  for (int i = t; i < tot; i += 512) atomicAdd(&h[stage[i] >> 16], 1);
  __syncthreads();
  // node scan (first 256 threads = 4 waves), padded to 16
  int grs = 0, p16 = 0, hc = 0, sv = 0;
  if (t < 256) {
    hc = h[t];
    p16 = (hc + 15) & ~15;
    sv = p16;
    for (int d = 1; d < 64; d <<= 1) {
      int y = __shfl_up(sv, d);
      if (lane >= d) sv += y;
    }
    if (lane == 63) nws[w] = sv;
  }
  __syncthreads();
  if (t < 256) {
    int a2 = 0;
    for (int j = 0; j < w; ++j) a2 += nws[j];
    sv += a2;                    // inclusive padded scan
    grs = r * SLAB + sv - p16;   // exclusive start (16-aligned)
    int v = r * 256 + t;
    if (v < NN) { rowstart[v] = grs; cnt[v] = hc; }
    off[t] = grs;
  }
  __syncthreads();
  // csr scatter
  for (int i = t; i < tot; i += 512) {
    u32 pk = stage[i];
    int pos = atomicAdd(&off[pk >> 16], 1);
    csr[pos] = (u16)(pk & 0xFFFFu);
  }
  __syncthreads();
  // sentinel pad
  if (t < 256) {
    int v = r * 256 + t;
    if (v < NN) {
      int end = grs + p16;
      for (int pos = off[t]; pos < end; ++pos) csr[pos] = (u16)NN;
    }
  }
  // dinv-scale gf -> g for this region's rows (2 threads per row)
  {
    int row = r * 256 + (t >> 1);
    int half = t & 1;
    if (row < NN) {
      float dv = rsqrtf((float)(h[t >> 1] + 1));
      const float* gr = gf + (size_t)row * 64 + half * 32;
      u16* go = g + (size_t)row * 64 + half * 32;
#pragma unroll
      for (int k2 = 0; k2 < 4; ++k2) {
        float4 a = *(const float4*)(gr + k2 * 8);
        float4 b4 = *(const float4*)(gr + k2 * 8 + 4);
        float v[8] = {a.x, a.y, a.z, a.w, b4.x, b4.y, b4.z, b4.w};
        short8 o8;
#pragma unroll
        for (int j = 0; j < 8; ++j) o8[j] = (short)f2b(v[j] * dv);
        *(short8*)(go + k2 * 8) = o8;
      }
    }
  }
}

// K2: layer-1 agg + relu + head projection, FOUR nodes/wave (64 gathers in
// flight), add-only inner loop (weights folded into g):
//   tvec[v] = dinv[v] * ( relu( dv*(sum g[s] + g[v]) + b1 ) . w2f )
__global__ __launch_bounds__(256) void k_agg1t(const u16* __restrict__ g,
                                               const int* __restrict__ cnt,
                                               const int* __restrict__ rowstart,
                                               const u16* __restrict__ csr,
                                               const u16* __restrict__ bias,
                                               const float* __restrict__ w2f,
                                               float* __restrict__ tvec) {
  int tid = threadIdx.x;
  int wave = tid >> 6, lane = tid & 63;
  int v = (blockIdx.x * 4 + wave) * 4;  // NN%16==0 -> v+3 < NN
  int rs[4], pd[4];
  float dvl[4], acc[4];
  int pm = 0;
#pragma unroll
  for (int n = 0; n < 4; ++n) {
    rs[n] = rowstart[v + n];
    int c = cnt[v + n];
    pd[n] = (c + 15) & ~15;
    dvl[n] = rsqrtf((float)(c + 1));
    acc[n] = b2f(g[(size_t)(v + n) * 64 + lane]);  // self term
    pm = pd[n] > pm ? pd[n] : pm;
  }
  for (int j = 0; j < pm; j += 16) {
    u32 cw[4][8];
    bool act[4];
#pragma unroll
    for (int n = 0; n < 4; ++n) {
      act[n] = j < pd[n];
      if (act[n]) {
        int b = rs[n] + j;
        uint4 c0 = *(const uint4*)(csr + b);
        uint4 c1 = *(const uint4*)(csr + b + 8);
        cw[n][0] = c0.x; cw[n][1] = c0.y; cw[n][2] = c0.z; cw[n][3] = c0.w;
        cw[n][4] = c1.x; cw[n][5] = c1.y; cw[n][6] = c1.z; cw[n][7] = c1.w;
      }
    }
    float hh[4][16];
#pragma unroll
    for (int n = 0; n < 4; ++n) {
      if (act[n]) {
#pragma unroll
        for (int i = 0; i < 8; ++i) {
          hh[n][2 * i] = b2f(g[(size_t)(cw[n][i] & 0xFFFFu) * 64 + lane]);
          hh[n][2 * i + 1] = b2f(g[(size_t)(cw[n][i] >> 16) * 64 + lane]);
        }
      }
    }
#pragma unroll
    for (int n = 0; n < 4; ++n) {
      if (act[n]) {
        float s0 = (hh[n][0] + hh[n][1]) + (hh[n][2] + hh[n][3]);
        float s1 = (hh[n][4] + hh[n][5]) + (hh[n][6] + hh[n][7]);
        float s2 = (hh[n][8] + hh[n][9]) + (hh[n][10] + hh[n][11]);
        float s3 = (hh[n][12] + hh[n][13]) + (hh[n][14] + hh[n][15]);
        acc[n] += (s0 + s1) + (s2 + s3);
      }
    }
  }
  float bv = b2f(bias[lane]);
  float wfv = w2f[lane];
  float val[4];
#pragma unroll
  for (int n = 0; n < 4; ++n) {
    val[n] = fmaxf(dvl[n] * acc[n] + bv, 0.0f) * wfv;
    for (int o = 32; o > 0; o >>= 1) val[n] += __shfl_xor(val[n], o);
  }
#pragma unroll
  for (int n = 0; n < 4; ++n)
    if (lane == n) tvec[v + n] = dvl[n] * val[n];
}

// K3: scalar agg + sigmoid: four nodes/wave, 16 lanes each.
// z[v] = dv*(sum tscaled[s] + tscaled[v]) + cbias; sentinel pads add 0.
__global__ __launch_bounds__(256) void k_aggz(const float* __restrict__ tvec,
                                              const int* __restrict__ rowstart,
                                              const int* __restrict__ cnt,
                                              const u16* __restrict__ csr,
                                              const float* __restrict__ cbias,
                                              void* __restrict__ out,
                                              const int* __restrict__ flags) {
  int tid = threadIdx.x;
  int wave = tid >> 6, lane = tid & 63;
  int sub = lane >> 4, slot = lane & 15;
  int v = blockIdx.x * 16 + wave * 4 + sub;  // NN%16==0 -> v < NN
  int rs = rowstart[v];
  int cv = cnt[v];
  int pdeg = (cv + 15) & ~15;
  float acc = 0.f;
  for (int j = slot; j < pdeg; j += 16) acc += tvec[csr[rs + j]];
  for (int o = 8; o > 0; o >>= 1) acc += __shfl_xor(acc, o);
  if (slot == 0) {
    float dv = rsqrtf((float)(cv + 1));
    float z = dv * (acc + tvec[v]) + cbias[0];
    float sg = 1.0f / (1.0f + __expf(-z));
    if (flags[0]) ((u16*)out)[v] = f2b(sg);
    else ((float*)out)[v] = sg;
  }
}

extern "C" void kernel_launch(void* const* d_in, const int* in_sizes, int n_in,
                              void* d_out, int out_size, void* d_ws, size_t ws_size,
                              hipStream_t stream) {
  const void* x = d_in[0];
  const int* ei = (const int*)d_in[1];
  const void* W1 = d_in[2];
  const u16* b1 = (const u16*)d_in[3];
  const void* W2 = d_in[4];
  const u16* b2 = (const u16*)d_in[5];
  const void* Wfc = d_in[6];
  const u16* bfc = (const u16*)d_in[7];

  int E = in_sizes[1] / 2;
  const int* src = ei;
  const int* dst = ei + E;

  char* base = (char*)d_ws;
  size_t off = 0;
  auto alloc = [&](size_t bytes) {
    void* p = base + off;
    off = (off + bytes + 255) & ~(size_t)255;
    return p;
  };
  int* flags = (int*)alloc(8 * 4);
  float* w2f = (float*)alloc(64 * 4);
  float* cbias = (float*)alloc(4);
  int* cnt = (int*)alloc((size_t)NN * 4);
  int* rowstart = (int*)alloc((size_t)NN * 4);
  u32* bucket = (u32*)alloc((size_t)NBINB * NREG * CAP2 * 4);  // 12.8 MB
  u8* cntm = (u8*)alloc((size_t)NBINB * NREG);                 // 100 KB
  u16* csr = (u16*)alloc((size_t)NREG * SLAB * 2);
  float* gf = (float*)alloc((size_t)NN * 64 * 4);              // unscaled h1
  u16* g = (u16*)alloc((size_t)(NN + 1) * 64 * 2);  // dinv-scaled h1 + 0 row
  float* tvec = (float*)alloc((size_t)(NN + 1) * 4);  // tscaled + 0 sentinel

  // K0) misc prep (1) || one-pass binning (512) || unscaled MFMA GEMM (782)
  k_prep_bin_gemm<<<1 + NBINB + NGEMB, 256, 0, stream>>>(
      (const u32*)x, in_sizes[0] / 2, W1, in_sizes[2] / 2, W2, in_sizes[4] / 2,
      Wfc, in_sizes[6] / 2, b2, bfc, w2f, cbias, flags, src, dst, E, bucket,
      cntm, x, gf, g, tvec);
  // K1) per-region assemble: cnt/rowstart/csr + dinv-scale gf -> g
  k_assemble<<<NREG, 512, 0, stream>>>(bucket, cntm, rowstart, cnt, csr, gf, g);
  // K2) layer-1 agg + relu + head projection -> tscaled
  k_agg1t<<<NN / 16, 256, 0, stream>>>(g, cnt, rowstart, csr, b1, w2f, tvec);
  // K3) scalar agg + sigmoid -> out
  k_aggz<<<NN / 16, 256, 0, stream>>>(tvec, rowstart, cnt, csr, cbias, d_out,
                                      flags);
}